// Round 2
// 548.825 us; speedup vs baseline: 1.1960x; 1.1960x over previous
//
#include <hip/hip_runtime.h>
#include <hip/hip_bf16.h>

// Problem constants
#define B_    16
#define CI    512
#define CO    512
#define HH    64
#define WW    64
#define NPIX  4096          // 64*64
#define KTAPS 9
#define KTOT  (CI * KTAPS)  // 4608
#define LEAK  0.2f

// Padded channels-last image: [b][66][66][512] bf16 (1-px halo absorbs SAME pad)
// Holds style-premultiplied image: x[b,y,x,i] * style[b,i]
#define PY 66
#define PX 66
#define IMGPAD_ELEMS ((size_t)B_ * PY * PX * CI)

typedef __attribute__((ext_vector_type(8))) __bf16  bf16x8;
typedef __attribute__((ext_vector_type(4))) float   floatx4;

// Direct global->LDS 16B staging. LDS dest is wave-uniform base + lane*16;
// global addr is per-lane (lets us pre-swizzle the SOURCE, rule #21).
__device__ __forceinline__ void load_lds16(const __bf16* g, __bf16* l) {
    __builtin_amdgcn_global_load_lds(
        (const __attribute__((address_space(1))) unsigned int*)g,
        (__attribute__((address_space(3))) unsigned int*)(unsigned int)(uintptr_t)l,
        16, 0, 0);
}

// ---------------------------------------------------------------- prep kernels

// style[b][i] = sum_w w_embs[b][w] * style_w[i][w] + style_b[i] + 1
__global__ void style_kernel(const float* __restrict__ w_embs,
                             const float* __restrict__ style_w,
                             const float* __restrict__ style_b,
                             float* __restrict__ style) {
    int b = blockIdx.y;
    int i = blockIdx.x * 256 + threadIdx.x;
    const float4* we = (const float4*)(w_embs + (size_t)b * 512);
    const float4* sw = (const float4*)(style_w + (size_t)i * 512);
    float acc = 0.f;
    #pragma unroll 8
    for (int k = 0; k < 128; ++k) {
        float4 a = we[k], c = sw[k];
        acc += a.x * c.x + a.y * c.y + a.z * c.z + a.w * c.w;
    }
    style[b * 512 + i] = acc + style_b[i] + 1.0f;
}

// w2[o][i] = sum_tap conv_w[o][i][tap]^2
__global__ void w2_kernel(const float* __restrict__ conv_w, float* __restrict__ w2) {
    int idx = blockIdx.x * 256 + threadIdx.x;   // o*512+i, 262144 total
    const float* p = conv_w + (size_t)idx * 9;
    float s = 0.f;
    #pragma unroll
    for (int t = 0; t < 9; ++t) s += p[t] * p[t];
    w2[idx] = s;
}

// invn[b][o] = 1/sqrt( sum_i w2[o][i] * style[b][i]^2 )
__global__ void invn_kernel(const float* __restrict__ w2,
                            const float* __restrict__ style,
                            float* __restrict__ invn) {
    __shared__ float st2[512];
    int b = blockIdx.y;
    int o = blockIdx.x * 256 + threadIdx.x;
    for (int i = threadIdx.x; i < 512; i += 256) {
        float s = style[b * 512 + i];
        st2[i] = s * s;
    }
    __syncthreads();
    const float* wr = w2 + (size_t)o * 512;
    float acc = 0.f;
    #pragma unroll 8
    for (int i = 0; i < 512; ++i) acc += wr[i] * st2[i];
    invn[b * 512 + o] = 1.0f / sqrtf(acc);
}

// Shared (batch-independent) bf16 weight, k-contiguous: wsh[o][tap*512 + i]
__global__ void wsh_kernel(const float* __restrict__ conv_w,
                           __bf16* __restrict__ wsh) {
    int o = blockIdx.x * 4 + (threadIdx.x >> 6);
    int i0 = (threadIdx.x & 63) * 8;
    const float* p = conv_w + ((size_t)o * 512 + i0) * 9;   // 72 contiguous floats
    float w[8][9];
    #pragma unroll
    for (int j = 0; j < 8; ++j)
        #pragma unroll
        for (int t = 0; t < 9; ++t) w[j][t] = p[j * 9 + t];
    __bf16* dstB = wsh + (size_t)o * KTOT + i0;
    #pragma unroll
    for (int t = 0; t < 9; ++t) {
        bf16x8 v;
        #pragma unroll
        for (int j = 0; j < 8; ++j) v[j] = (__bf16)w[j][t];
        *(bf16x8*)(dstB + t * 512) = v;
    }
}

// Zero only the halo ring of imgpad (260 px/batch instead of 71 MB memset)
__global__ void halo_kernel(__bf16* __restrict__ imgpad) {
    int t = blockIdx.x * 256 + threadIdx.x;
    if (t >= B_ * 260 * 64) return;
    int c8 = t & 63;
    int rest = t >> 6;
    int px = rest % 260;
    int b = rest / 260;
    int y, x;
    if (px < 66)       { y = 0;  x = px; }
    else if (px < 132) { y = 65; x = px - 66; }
    else { int s = px - 132; y = 1 + (s >> 1); x = (s & 1) * 65; }
    float4 z = {0.f, 0.f, 0.f, 0.f};
    *(float4*)&imgpad[(((size_t)b * PY + y) * PX + x) * 512 + c8 * 8] = z;
}

// NCHW fp32 -> padded channels-last bf16 [b][y][x][i], premultiplied by style[b][i]
__global__ void imgpad_kernel(const float* __restrict__ imgs,
                              const float* __restrict__ style,
                              __bf16* __restrict__ imgpad) {
    __shared__ float tile[32][65];
    int ic = blockIdx.x, h = blockIdx.y, b = blockIdx.z;
    int t = threadIdx.x;
    int i0 = ic * 32;
    {
        int li = t >> 3;            // 0..31 channel within chunk
        int w0 = (t & 7) * 8;       // 0..56
        const float* src = imgs + (((size_t)(b * 512 + i0 + li) * 64 + h) * 64 + w0);
        float4 v0 = ((const float4*)src)[0];
        float4 v1 = ((const float4*)src)[1];
        tile[li][w0 + 0] = v0.x; tile[li][w0 + 1] = v0.y;
        tile[li][w0 + 2] = v0.z; tile[li][w0 + 3] = v0.w;
        tile[li][w0 + 4] = v1.x; tile[li][w0 + 5] = v1.y;
        tile[li][w0 + 6] = v1.z; tile[li][w0 + 7] = v1.w;
    }
    __syncthreads();
    {
        int w  = t >> 2;            // 0..63
        int c0 = (t & 3) * 8;       // 0,8,16,24
        float st[8];
        #pragma unroll
        for (int j = 0; j < 8; ++j) st[j] = style[b * 512 + i0 + c0 + j];
        bf16x8 v;
        #pragma unroll
        for (int j = 0; j < 8; ++j) v[j] = (__bf16)(tile[c0 + j][w] * st[j]);
        __bf16* dst = imgpad + (((size_t)b * PY + (h + 1)) * PX + (w + 1)) * 512 + i0 + c0;
        *(bf16x8*)dst = v;
    }
}

// ---------------------------------------------------------------- main conv
//
// 256x256 tile, BK=64, 8 waves (2M x 4N), 128 KiB LDS, 4 phases per K-tile
// (8-phase-per-2-tiles schedule, T2+T3+T4+T5):
//   phase = { ds_read frags | stage one half-tile | barrier |
//             setprio(1) 16xMFMA setprio(0) | barrier }
// Staging pipeline (steady state, per tile t with buf p = t&1):
//   ph0: stage A-half0(t+1) -> As[p^1]   (A(t-1) reads done at t-1.ph3 bar2)
//   ph1: stage A-half1(t+1) -> As[p^1]
//   ph2: stage B-half0(t+2) -> Bs[p]     (B(t) reads all done in ph0)
//   ph3: stage B-half1(t+2) -> Bs[p];  vmcnt(4)  (leaves B(t+2) in flight)
// LDS swizzle: linear LDS dest (global_load_lds requirement); global SOURCE
// k-slot permuted per-lane (slot = (l&7)^(l>>3)); frag reads use
// slot = kslot ^ (row&7)  -> 8 lanes/slot on distinct rows = b128 floor.
//
// Race-freedom argument (raw s_barrier, no full drains):
//  - B(t) ds_reads (ph0) complete before each wave's MFMA_PH(0) (compiler
//    lgkmcnt); in-order lgkm completion means they are done before any wave
//    passes ph1's end barrier; B(t+2) staging into the same region issues in
//    ph2 — two barriers later. No WAR hazard.
//  - A(t+1) / B(t+1) staging completion is enforced by the single counted
//    vmcnt(4) at tile end (drains everything except B(t+2)'s 4 loads).

#define BM 256
#define BN 256
#define BK 64
#define NT 72   // K tiles: 9 taps * (512/64)

#define BAR() { __builtin_amdgcn_s_barrier(); __builtin_amdgcn_sched_barrier(0); }

// frag reads: PTR carries lane base (+wave row block, +r16*128, +slot for its ks)
#define RA(PTR, BUFL, MI) (*(const bf16x8*)((PTR) + (BUFL) * 32768 + (MI) * 2048))
#define RB(PTR, BUFL, NI) (*(const bf16x8*)((PTR) + (BUFL) * 32768 + (NI) * 2048))

// staging LDS dests (wave-uniform)
#define DSTA(BUFL, H, J) (&As[BUFL][(((H) * 128 + (J) * 64) + (wv << 3)) * 64])
#define DSTB(BUFL, H, J) (&Bs[BUFL][(((H) * 128 + (J) * 64) + (wv << 3)) * 64])

#define MFMA_PH(Q)                                                            \
    __builtin_amdgcn_s_setprio(1);                                            \
    _Pragma("unroll") for (int e = 0; e < 2; ++e) {                           \
      _Pragma("unroll") for (int ni = 0; ni < 4; ++ni) {                      \
        acc[2*(Q)+e][ni] = __builtin_amdgcn_mfma_f32_16x16x32_bf16(           \
            af[e][0], bf[ni][0], acc[2*(Q)+e][ni], 0, 0, 0);                  \
        acc[2*(Q)+e][ni] = __builtin_amdgcn_mfma_f32_16x16x32_bf16(           \
            af[e][1], bf[ni][1], acc[2*(Q)+e][ni], 0, 0, 0);                  \
      }                                                                       \
    }                                                                         \
    __builtin_amdgcn_s_setprio(0);

#define TILE(BUF, T, DO_A, DO_B, TAIL) {                                      \
    /* phase 0: all B-frags + A mi 0,1; stage A-half0(T+1) */                 \
    _Pragma("unroll") for (int ni = 0; ni < 4; ++ni) {                        \
        bf[ni][0] = RB(ldsB0, BUF, ni); bf[ni][1] = RB(ldsB1, BUF, ni);       \
    }                                                                         \
    af[0][0] = RA(ldsA0, BUF, 0); af[0][1] = RA(ldsA1, BUF, 0);               \
    af[1][0] = RA(ldsA0, BUF, 1); af[1][1] = RA(ldsA1, BUF, 1);               \
    if (DO_A) { int ka = ((T) + 1) * 64;                                      \
        load_lds16(aG00 + ka, DSTA((BUF) ^ 1, 0, 0));                         \
        load_lds16(aG01 + ka, DSTA((BUF) ^ 1, 0, 1)); }                       \
    BAR();                                                                    \
    MFMA_PH(0)                                                                \
    BAR();                                                                    \
    /* phase 1: A mi 2,3; stage A-half1(T+1) */                               \
    af[0][0] = RA(ldsA0, BUF, 2); af[0][1] = RA(ldsA1, BUF, 2);               \
    af[1][0] = RA(ldsA0, BUF, 3); af[1][1] = RA(ldsA1, BUF, 3);               \
    if (DO_A) { int ka = ((T) + 1) * 64;                                      \
        load_lds16(aG10 + ka, DSTA((BUF) ^ 1, 1, 0));                         \
        load_lds16(aG11 + ka, DSTA((BUF) ^ 1, 1, 1)); }                       \
    BAR();                                                                    \
    MFMA_PH(1)                                                                \
    BAR();                                                                    \
    /* phase 2: A mi 4,5; stage B-half0(T+2) */                               \
    af[0][0] = RA(ldsA0, BUF, 4); af[0][1] = RA(ldsA1, BUF, 4);               \
    af[1][0] = RA(ldsA0, BUF, 5); af[1][1] = RA(ldsA1, BUF, 5);               \
    int bd2_##BUF = 0; (void)bd2_##BUF;                                       \
    if (DO_B) { int t2 = (T) + 2; int tap2 = t2 >> 3; int ic2 = t2 & 7;       \
        int dy2 = tap2 / 3, dx2 = tap2 - 3 * dy2;                             \
        bd2_##BUF = (dy2 * PX + dx2) * 512 + ic2 * 64;                        \
        load_lds16(bG00 + bd2_##BUF, DSTB(BUF, 0, 0));                        \
        load_lds16(bG01 + bd2_##BUF, DSTB(BUF, 0, 1)); }                      \
    BAR();                                                                    \
    MFMA_PH(2)                                                                \
    BAR();                                                                    \
    /* phase 3: A mi 6,7; stage B-half1(T+2); counted vmcnt */                \
    af[0][0] = RA(ldsA0, BUF, 6); af[0][1] = RA(ldsA1, BUF, 6);               \
    af[1][0] = RA(ldsA0, BUF, 7); af[1][1] = RA(ldsA1, BUF, 7);               \
    if (DO_B) {                                                               \
        load_lds16(bG10 + bd2_##BUF, DSTB(BUF, 1, 0));                        \
        load_lds16(bG11 + bd2_##BUF, DSTB(BUF, 1, 1)); }                      \
    BAR();                                                                    \
    MFMA_PH(3)                                                                \
    if (TAIL) { asm volatile("s_waitcnt vmcnt(0)" ::: "memory"); }            \
    else      { asm volatile("s_waitcnt vmcnt(4)" ::: "memory"); }            \
    __builtin_amdgcn_sched_barrier(0);                                        \
    BAR();                                                                    \
}

// out[b,o,p] = leaky( invn[b,o] * (wsh[o,:] . ximg[b,p,:]) + conv_b[o] + noise*nw )
__global__ __launch_bounds__(512, 2) void conv_kernel(
    const __bf16* __restrict__ wsh,
    const __bf16* __restrict__ imgpad,
    const float*  __restrict__ invn,
    const float*  __restrict__ conv_b,
    const float*  __restrict__ noise,
    const float*  __restrict__ nw_p,
    float* __restrict__ out)
{
    __shared__ __attribute__((aligned(16))) __bf16 As[2][BM * BK];  // 64 KiB
    __shared__ __attribute__((aligned(16))) __bf16 Bs[2][BN * BK];  // 64 KiB

    const int tid = threadIdx.x;
    const int nt = blockIdx.x, mt = blockIdx.y, b = blockIdx.z;
    const int n0 = nt * BN, m0 = mt * BM;

    const int lane = tid & 63;
    const int wv = tid >> 6;          // 0..7
    const int wmi = wv & 1;           // M wave index (2)
    const int wni = wv >> 1;          // N wave index (4)

    const __bf16* iB = imgpad + (size_t)b * PY * PX * CI;

    // ---- staging per-thread constants
    const int r0   = (wv << 3) + (lane >> 3);        // 0..63: row within 64-row quarter
    const int ks_g = (lane & 7) ^ (lane >> 3);       // pre-swizzled global k-slot

    // A sources (h,j): row = m0 + h*128 + j*64 + r0, k = tile*64 + ks_g*8
    const __bf16* aG00 = wsh + (size_t)(m0 +   0 +  0 + r0) * KTOT + ks_g * 8;
    const __bf16* aG01 = wsh + (size_t)(m0 +   0 + 64 + r0) * KTOT + ks_g * 8;
    const __bf16* aG10 = wsh + (size_t)(m0 + 128 +  0 + r0) * KTOT + ks_g * 8;
    const __bf16* aG11 = wsh + (size_t)(m0 + 128 + 64 + r0) * KTOT + ks_g * 8;

    // B sources (h,j): pixel p = n0 + h*128 + j*64 + r0 -> y = nt*4+2h+j, x = r0
    const __bf16* bG00 = iB + ((size_t)(nt * 4 + 0) * PX + r0) * 512 + ks_g * 8;
    const __bf16* bG01 = iB + ((size_t)(nt * 4 + 1) * PX + r0) * 512 + ks_g * 8;
    const __bf16* bG10 = iB + ((size_t)(nt * 4 + 2) * PX + r0) * 512 + ks_g * 8;
    const __bf16* bG11 = iB + ((size_t)(nt * 4 + 3) * PX + r0) * 512 + ks_g * 8;

    // ---- fragment-read per-lane bases (byte math; slot = kslot ^ (row&7))
    const int r16 = lane & 15, q4 = lane >> 4, r7 = lane & 7;
    const int s0 = (q4 ^ r7) << 4;                   // ks=0 slot bytes
    const char* ldsA0 = (const char*)&As[0][0] + wmi * 16384 + r16 * 128 + s0;
    const char* ldsA1 = (const char*)&As[0][0] + wmi * 16384 + r16 * 128 + (s0 ^ 64);
    const char* ldsB0 = (const char*)&Bs[0][0] + wni * 8192  + r16 * 128 + s0;
    const char* ldsB1 = (const char*)&Bs[0][0] + wni * 8192  + r16 * 128 + (s0 ^ 64);

    floatx4 acc[8][4];
    #pragma unroll
    for (int mi = 0; mi < 8; ++mi)
        #pragma unroll
        for (int ni = 0; ni < 4; ++ni)
            acc[mi][ni] = (floatx4)(0.f);

    // ---- prologue: A(0), B(0), B(1); leave B(1) in flight
    load_lds16(aG00, DSTA(0, 0, 0));
    load_lds16(aG01, DSTA(0, 0, 1));
    load_lds16(aG10, DSTA(0, 1, 0));
    load_lds16(aG11, DSTA(0, 1, 1));
    load_lds16(bG00, DSTB(0, 0, 0));          // bd(0) = 0 (tap0, ic0)
    load_lds16(bG01, DSTB(0, 0, 1));
    load_lds16(bG10, DSTB(0, 1, 0));
    load_lds16(bG11, DSTB(0, 1, 1));
    load_lds16(bG00 + 64, DSTB(1, 0, 0));     // bd(1) = 64 (tap0, ic1)
    load_lds16(bG01 + 64, DSTB(1, 0, 1));
    load_lds16(bG10 + 64, DSTB(1, 1, 0));
    load_lds16(bG11 + 64, DSTB(1, 1, 1));
    asm volatile("s_waitcnt vmcnt(4)" ::: "memory");
    __builtin_amdgcn_sched_barrier(0);
    BAR();

    bf16x8 af[2][2];
    bf16x8 bf[4][2];

    #pragma unroll 1
    for (int it = 0; it < 35; ++it) {
        int t0 = it * 2;
        TILE(0, t0,     true, true, false)
        TILE(1, t0 + 1, true, true, false)
    }
    // tiles 70, 71: no B prefetch left; tile 70 stages A(71) then drains
    TILE(0, 70, true,  false, true)
    TILE(1, 71, false, false, true)

    // ---- epilogue: * invn[b,o] + conv_b + noise*nw, LeakyReLU(0.2)
    float nwv = nw_p[0];
    #pragma unroll
    for (int ni = 0; ni < 4; ++ni) {
        int col = n0 + wni * 64 + ni * 16 + r16;         // pixel
        float nz = noise[b * NPIX + col] * nwv;
        #pragma unroll
        for (int mi = 0; mi < 8; ++mi) {
            int rowo = m0 + wmi * 128 + mi * 16 + q4 * 4; // output channel base
            #pragma unroll
            for (int rr = 0; rr < 4; ++rr) {
                float sc = invn[b * 512 + rowo + rr];
                float vv = acc[mi][ni][rr] * sc + conv_b[rowo + rr] + nz;
                out[(((size_t)b * CO + rowo + rr) << 12) + col] = vv >= 0.f ? vv : LEAK * vv;
            }
        }
    }
}

// ---------------------------------------------------------------- launch

extern "C" void kernel_launch(void* const* d_in, const int* in_sizes, int n_in,
                              void* d_out, int out_size, void* d_ws, size_t ws_size,
                              hipStream_t stream) {
    const float* imgs    = (const float*)d_in[0];
    const float* w_embs  = (const float*)d_in[1];
    const float* noise   = (const float*)d_in[2];
    const float* conv_w  = (const float*)d_in[3];
    const float* conv_b  = (const float*)d_in[4];
    const float* style_w = (const float*)d_in[5];
    const float* style_b = (const float*)d_in[6];
    const float* nw      = (const float*)d_in[7];
    float* out = (float*)d_out;

    char* ws = (char*)d_ws;
    size_t off = 0;
    __bf16* wsh = (__bf16*)(ws + off);       off += (size_t)CO * KTOT * 2;           // 4.7 MB
    __bf16* imgpad = (__bf16*)(ws + off);    off += IMGPAD_ELEMS * 2;                // 71.4 MB
    float* style = (float*)(ws + off);       off += (size_t)B_ * CI * 4;
    float* invn  = (float*)(ws + off);       off += (size_t)B_ * CO * 4;
    float* w2    = (float*)(ws + off);       off += (size_t)CO * CI * 4;

    style_kernel<<<dim3(2, B_), 256, 0, stream>>>(w_embs, style_w, style_b, style);
    w2_kernel<<<dim3(1024), 256, 0, stream>>>(conv_w, w2);
    invn_kernel<<<dim3(2, B_), 256, 0, stream>>>(w2, style, invn);
    wsh_kernel<<<dim3(CO / 4), 256, 0, stream>>>(conv_w, wsh);
    halo_kernel<<<dim3((B_ * 260 * 64 + 255) / 256), 256, 0, stream>>>(imgpad);
    imgpad_kernel<<<dim3(16, HH, B_), 256, 0, stream>>>(imgs, style, imgpad);
    conv_kernel<<<dim3(NPIX / BN, CO / BM, B_), 512, 0, stream>>>(
        wsh, imgpad, invn, conv_b, noise, nw, out);
}

// Round 3
// 529.640 us; speedup vs baseline: 1.2393x; 1.0362x over previous
//
#include <hip/hip_runtime.h>
#include <hip/hip_bf16.h>

// Problem constants
#define B_    16
#define CI    512
#define CO    512
#define HH    64
#define WW    64
#define NPIX  4096          // 64*64
#define KTAPS 9
#define KTOT  (CI * KTAPS)  // 4608
#define LEAK  0.2f

// Padded channels-last image: [b][66][66][512] bf16 (1-px halo absorbs SAME pad)
// Holds style-premultiplied image: x[b,y,x,i] * style[b,i]
#define PY 66
#define PX 66
#define IMGPAD_ELEMS ((size_t)B_ * PY * PX * CI)

typedef __attribute__((ext_vector_type(8))) __bf16  bf16x8;
typedef __attribute__((ext_vector_type(4))) float   floatx4;

// Direct global->LDS 16B staging. LDS dest is wave-uniform base + lane*16;
// global addr is per-lane (lets us pre-swizzle the SOURCE, rule #21).
__device__ __forceinline__ void load_lds16(const __bf16* g, __bf16* l) {
    __builtin_amdgcn_global_load_lds(
        (const __attribute__((address_space(1))) unsigned int*)g,
        (__attribute__((address_space(3))) unsigned int*)(unsigned int)(uintptr_t)l,
        16, 0, 0);
}

// ---------------------------------------------------------------- prep kernels

// style[b][i] = sum_w w_embs[b][w] * style_w[i][w] + style_b[i] + 1
__global__ void style_kernel(const float* __restrict__ w_embs,
                             const float* __restrict__ style_w,
                             const float* __restrict__ style_b,
                             float* __restrict__ style) {
    int b = blockIdx.y;
    int i = blockIdx.x * 256 + threadIdx.x;
    const float4* we = (const float4*)(w_embs + (size_t)b * 512);
    const float4* sw = (const float4*)(style_w + (size_t)i * 512);
    float acc = 0.f;
    #pragma unroll 8
    for (int k = 0; k < 128; ++k) {
        float4 a = we[k], c = sw[k];
        acc += a.x * c.x + a.y * c.y + a.z * c.z + a.w * c.w;
    }
    style[b * 512 + i] = acc + style_b[i] + 1.0f;
}

// w2[o][i] = sum_tap conv_w[o][i][tap]^2
__global__ void w2_kernel(const float* __restrict__ conv_w, float* __restrict__ w2) {
    int idx = blockIdx.x * 256 + threadIdx.x;   // o*512+i, 262144 total
    const float* p = conv_w + (size_t)idx * 9;
    float s = 0.f;
    #pragma unroll
    for (int t = 0; t < 9; ++t) s += p[t] * p[t];
    w2[idx] = s;
}

// invn[b][o] = 1/sqrt( sum_i w2[o][i] * style[b][i]^2 )
__global__ void invn_kernel(const float* __restrict__ w2,
                            const float* __restrict__ style,
                            float* __restrict__ invn) {
    __shared__ float st2[512];
    int b = blockIdx.y;
    int o = blockIdx.x * 256 + threadIdx.x;
    for (int i = threadIdx.x; i < 512; i += 256) {
        float s = style[b * 512 + i];
        st2[i] = s * s;
    }
    __syncthreads();
    const float* wr = w2 + (size_t)o * 512;
    float acc = 0.f;
    #pragma unroll 8
    for (int i = 0; i < 512; ++i) acc += wr[i] * st2[i];
    invn[b * 512 + o] = 1.0f / sqrtf(acc);
}

// Shared (batch-independent) bf16 weight, k-contiguous: wsh[o][tap*512 + i]
__global__ void wsh_kernel(const float* __restrict__ conv_w,
                           __bf16* __restrict__ wsh) {
    int o = blockIdx.x * 4 + (threadIdx.x >> 6);
    int i0 = (threadIdx.x & 63) * 8;
    const float* p = conv_w + ((size_t)o * 512 + i0) * 9;   // 72 contiguous floats
    float w[8][9];
    #pragma unroll
    for (int j = 0; j < 8; ++j)
        #pragma unroll
        for (int t = 0; t < 9; ++t) w[j][t] = p[j * 9 + t];
    __bf16* dstB = wsh + (size_t)o * KTOT + i0;
    #pragma unroll
    for (int t = 0; t < 9; ++t) {
        bf16x8 v;
        #pragma unroll
        for (int j = 0; j < 8; ++j) v[j] = (__bf16)w[j][t];
        *(bf16x8*)(dstB + t * 512) = v;
    }
}

// Zero only the halo ring of imgpad (260 px/batch instead of 71 MB memset)
__global__ void halo_kernel(__bf16* __restrict__ imgpad) {
    int t = blockIdx.x * 256 + threadIdx.x;
    if (t >= B_ * 260 * 64) return;
    int c8 = t & 63;
    int rest = t >> 6;
    int px = rest % 260;
    int b = rest / 260;
    int y, x;
    if (px < 66)       { y = 0;  x = px; }
    else if (px < 132) { y = 65; x = px - 66; }
    else { int s = px - 132; y = 1 + (s >> 1); x = (s & 1) * 65; }
    float4 z = {0.f, 0.f, 0.f, 0.f};
    *(float4*)&imgpad[(((size_t)b * PY + y) * PX + x) * 512 + c8 * 8] = z;
}

// NCHW fp32 -> padded channels-last bf16 [b][y][x][i], premultiplied by style.
// 64-channel blocks: stores are 128 B contiguous segments (full L2 lines),
// half the block count of the old 32-channel version.
__global__ void imgpad_kernel(const float* __restrict__ imgs,
                              const float* __restrict__ style,
                              __bf16* __restrict__ imgpad) {
    __shared__ float tile[64][65];
    int ic = blockIdx.x, h = blockIdx.y, b = blockIdx.z;
    int t = threadIdx.x;
    int i0 = ic * 64;
    {
        int li = t >> 2;            // 0..63 channel within chunk
        int w0 = (t & 3) * 16;      // 0,16,32,48
        const float* src = imgs + (((size_t)(b * 512 + i0 + li) * 64 + h) * 64 + w0);
        float4 v0 = ((const float4*)src)[0];
        float4 v1 = ((const float4*)src)[1];
        float4 v2 = ((const float4*)src)[2];
        float4 v3 = ((const float4*)src)[3];
        tile[li][w0 +  0] = v0.x; tile[li][w0 +  1] = v0.y;
        tile[li][w0 +  2] = v0.z; tile[li][w0 +  3] = v0.w;
        tile[li][w0 +  4] = v1.x; tile[li][w0 +  5] = v1.y;
        tile[li][w0 +  6] = v1.z; tile[li][w0 +  7] = v1.w;
        tile[li][w0 +  8] = v2.x; tile[li][w0 +  9] = v2.y;
        tile[li][w0 + 10] = v2.z; tile[li][w0 + 11] = v2.w;
        tile[li][w0 + 12] = v3.x; tile[li][w0 + 13] = v3.y;
        tile[li][w0 + 14] = v3.z; tile[li][w0 + 15] = v3.w;
    }
    __syncthreads();
    {
        int c0 = (t & 7) * 8;       // 0..56: 8 lanes x 16 B = 128 B segments
        float st[8];
        #pragma unroll
        for (int j = 0; j < 8; ++j) st[j] = style[b * 512 + i0 + c0 + j];
        #pragma unroll
        for (int g = 0; g < 2; ++g) {
            int w = (t >> 3) + g * 32;   // 0..63
            bf16x8 v;
            #pragma unroll
            for (int j = 0; j < 8; ++j) v[j] = (__bf16)(tile[c0 + j][w] * st[j]);
            __bf16* dst = imgpad + (((size_t)b * PY + (h + 1)) * PX + (w + 1)) * 512 + i0 + c0;
            *(bf16x8*)dst = v;
        }
    }
}

// ---------------------------------------------------------------- main conv
//
// 256x256 tile, BK=64, 8 waves (2M x 4N), 128 KiB LDS.
// 4 MFMA clusters (16 each) per K-tile, but only TWO barriers per tile:
//   [tile start]
//   ph0: read 8 bf + 4 af ; stage A-half0(t+1) ; M0
//   ph1: read 4 af        ; stage A-half1(t+1) ; M1
//   BAR          <- B-region guard (see hazards below)
//   ph2: read 4 af        ; stage B-half0(t+2) ; M2
//   ph3: read 4 af        ; stage B-half1(t+2) ; M3
//   vmcnt(4) ; BAR
// No barrier between a read cluster and its MFMA cluster: all frag reads come
// from buffers staged >=1 tile ago; waves drift through the phases, so the
// LDS pipe (frag reads, ~768 cyc/CU/tile) overlaps the matrix pipe
// (~616 cyc/SIMD/tile) instead of serializing (the round-2 8-barrier lockstep
// measured 48.6% MfmaUtil = serialized; model says overlap -> ~60%).
//
// Hazard ledger (cross-wave, raw s_barrier):
//  - Bs[BUF] writes (B(t+2), ph2/3) vs Bs[BUF] reads (bf, ph0): every wave's
//    bf reads are retired before its M0/M1 issue (MFMA operand lgkm wait);
//    all waves are past M1 at the mid BAR; stage issues are after it.  OK.
//  - As[BUF^1] writes (A(t+1), ph0/1) vs As[BUF^1] reads (t-1's af): those
//    reads retired before t-1's M3 -> before t-1's end BAR.  OK.
//  - Staging completion before consumption: end-of-tile vmcnt(4) drains
//    A(t+1) and B(t+1) (issue order: ... B(t+1) [t-1 ph2/3], A(t+1) [t ph0/1],
//    B(t+2) [t ph2/3]; <=4 outstanding = newest 4 = B(t+2)); barrier makes
//    that visible to all waves.  Tail tiles (no B stage) drain to 0.
// LDS swizzle: linear LDS dest (global_load_lds requirement); global SOURCE
// k-slot permuted per-lane (slot = (l&7)^(l>>3)); frag reads use
// slot = kslot ^ (row&7)  -> 8 lanes/slot on distinct rows = b128 floor.
// (round 2 measured: SQ_LDS_BANK_CONFLICT == 0)

#define BM 256
#define BN 256
#define BK 64
#define NT 72   // K tiles: 9 taps * (512/64)

#define BAR() { __builtin_amdgcn_sched_barrier(0);                            \
                __builtin_amdgcn_s_barrier();                                 \
                __builtin_amdgcn_sched_barrier(0); }

// frag reads: PTR carries lane base (+wave row block, +r16*128, +slot for its ks)
#define RA(PTR, BUFL, MI) (*(const bf16x8*)((PTR) + (BUFL) * 32768 + (MI) * 2048))
#define RB(PTR, BUFL, NI) (*(const bf16x8*)((PTR) + (BUFL) * 32768 + (NI) * 2048))

// staging LDS dests (wave-uniform)
#define DSTA(BUFL, H, J) (&As[BUFL][(((H) * 128 + (J) * 64) + (wv << 3)) * 64])
#define DSTB(BUFL, H, J) (&Bs[BUFL][(((H) * 128 + (J) * 64) + (wv << 3)) * 64])

#define MFMA_PH(Q)                                                            \
    __builtin_amdgcn_s_setprio(1);                                            \
    _Pragma("unroll") for (int e = 0; e < 2; ++e) {                           \
      _Pragma("unroll") for (int ni = 0; ni < 4; ++ni) {                      \
        acc[2*(Q)+e][ni] = __builtin_amdgcn_mfma_f32_16x16x32_bf16(           \
            af[e][0], bf[ni][0], acc[2*(Q)+e][ni], 0, 0, 0);                  \
        acc[2*(Q)+e][ni] = __builtin_amdgcn_mfma_f32_16x16x32_bf16(           \
            af[e][1], bf[ni][1], acc[2*(Q)+e][ni], 0, 0, 0);                  \
      }                                                                       \
    }                                                                         \
    __builtin_amdgcn_s_setprio(0);

#define TILE(BUF, T, DO_A, DO_B, VME) {                                       \
    /* ph0: all B-frags + A mi0,1; stage A-half0(T+1) */                      \
    _Pragma("unroll") for (int ni = 0; ni < 4; ++ni) {                        \
        bf[ni][0] = RB(ldsB0, BUF, ni); bf[ni][1] = RB(ldsB1, BUF, ni);       \
    }                                                                         \
    af[0][0] = RA(ldsA0, BUF, 0); af[0][1] = RA(ldsA1, BUF, 0);               \
    af[1][0] = RA(ldsA0, BUF, 1); af[1][1] = RA(ldsA1, BUF, 1);               \
    if (DO_A) { int ka = ((T) + 1) * 64;                                      \
        load_lds16(aG00 + ka, DSTA((BUF) ^ 1, 0, 0));                         \
        load_lds16(aG01 + ka, DSTA((BUF) ^ 1, 0, 1)); }                       \
    MFMA_PH(0)                                                                \
    /* ph1: A mi2,3; stage A-half1(T+1) */                                    \
    af[0][0] = RA(ldsA0, BUF, 2); af[0][1] = RA(ldsA1, BUF, 2);               \
    af[1][0] = RA(ldsA0, BUF, 3); af[1][1] = RA(ldsA1, BUF, 3);               \
    if (DO_A) { int ka = ((T) + 1) * 64;                                      \
        load_lds16(aG10 + ka, DSTA((BUF) ^ 1, 1, 0));                         \
        load_lds16(aG11 + ka, DSTA((BUF) ^ 1, 1, 1)); }                       \
    MFMA_PH(1)                                                                \
    BAR();   /* B-region guard */                                             \
    /* ph2: A mi4,5; stage B-half0(T+2) */                                    \
    af[0][0] = RA(ldsA0, BUF, 4); af[0][1] = RA(ldsA1, BUF, 4);               \
    af[1][0] = RA(ldsA0, BUF, 5); af[1][1] = RA(ldsA1, BUF, 5);               \
    int bd2_##BUF = 0; (void)bd2_##BUF;                                       \
    if (DO_B) { int t2 = (T) + 2; int tap2 = t2 >> 3; int ic2 = t2 & 7;       \
        int dy2 = tap2 / 3, dx2 = tap2 - 3 * dy2;                             \
        bd2_##BUF = (dy2 * PX + dx2) * 512 + ic2 * 64;                        \
        load_lds16(bG00 + bd2_##BUF, DSTB(BUF, 0, 0));                        \
        load_lds16(bG01 + bd2_##BUF, DSTB(BUF, 0, 1)); }                      \
    MFMA_PH(2)                                                                \
    /* ph3: A mi6,7; stage B-half1(T+2); counted vmcnt */                     \
    af[0][0] = RA(ldsA0, BUF, 6); af[0][1] = RA(ldsA1, BUF, 6);               \
    af[1][0] = RA(ldsA0, BUF, 7); af[1][1] = RA(ldsA1, BUF, 7);               \
    if (DO_B) {                                                               \
        load_lds16(bG10 + bd2_##BUF, DSTB(BUF, 1, 0));                        \
        load_lds16(bG11 + bd2_##BUF, DSTB(BUF, 1, 1)); }                      \
    MFMA_PH(3)                                                                \
    asm volatile("s_waitcnt vmcnt(" #VME ")" ::: "memory");                   \
    __builtin_amdgcn_sched_barrier(0);                                        \
    BAR();                                                                    \
}

// out[b,o,p] = leaky( invn[b,o] * (wsh[o,:] . ximg[b,p,:]) + conv_b[o] + noise*nw )
__global__ __launch_bounds__(512, 2) void conv_kernel(
    const __bf16* __restrict__ wsh,
    const __bf16* __restrict__ imgpad,
    const float*  __restrict__ invn,
    const float*  __restrict__ conv_b,
    const float*  __restrict__ noise,
    const float*  __restrict__ nw_p,
    float* __restrict__ out)
{
    __shared__ __attribute__((aligned(16))) __bf16 As[2][BM * BK];  // 64 KiB
    __shared__ __attribute__((aligned(16))) __bf16 Bs[2][BN * BK];  // 64 KiB

    const int tid = threadIdx.x;
    const int nt = blockIdx.x, mt = blockIdx.y, b = blockIdx.z;
    const int n0 = nt * BN, m0 = mt * BM;

    const int lane = tid & 63;
    const int wv = tid >> 6;          // 0..7
    const int wmi = wv & 1;           // M wave index (2)
    const int wni = wv >> 1;          // N wave index (4)

    const __bf16* iB = imgpad + (size_t)b * PY * PX * CI;

    // ---- staging per-thread constants
    const int r0   = (wv << 3) + (lane >> 3);        // 0..63: row within 64-row quarter
    const int ks_g = (lane & 7) ^ (lane >> 3);       // pre-swizzled global k-slot

    // A sources (h,j): row = m0 + h*128 + j*64 + r0, k = tile*64 + ks_g*8
    const __bf16* aG00 = wsh + (size_t)(m0 +   0 +  0 + r0) * KTOT + ks_g * 8;
    const __bf16* aG01 = wsh + (size_t)(m0 +   0 + 64 + r0) * KTOT + ks_g * 8;
    const __bf16* aG10 = wsh + (size_t)(m0 + 128 +  0 + r0) * KTOT + ks_g * 8;
    const __bf16* aG11 = wsh + (size_t)(m0 + 128 + 64 + r0) * KTOT + ks_g * 8;

    // B sources (h,j): pixel p = n0 + h*128 + j*64 + r0 -> y = nt*4+2h+j, x = r0
    const __bf16* bG00 = iB + ((size_t)(nt * 4 + 0) * PX + r0) * 512 + ks_g * 8;
    const __bf16* bG01 = iB + ((size_t)(nt * 4 + 1) * PX + r0) * 512 + ks_g * 8;
    const __bf16* bG10 = iB + ((size_t)(nt * 4 + 2) * PX + r0) * 512 + ks_g * 8;
    const __bf16* bG11 = iB + ((size_t)(nt * 4 + 3) * PX + r0) * 512 + ks_g * 8;

    // ---- fragment-read per-lane bases (byte math; slot = kslot ^ (row&7))
    const int r16 = lane & 15, q4 = lane >> 4, r7 = lane & 7;
    const int s0 = (q4 ^ r7) << 4;                   // ks=0 slot bytes
    const char* ldsA0 = (const char*)&As[0][0] + wmi * 16384 + r16 * 128 + s0;
    const char* ldsA1 = (const char*)&As[0][0] + wmi * 16384 + r16 * 128 + (s0 ^ 64);
    const char* ldsB0 = (const char*)&Bs[0][0] + wni * 8192  + r16 * 128 + s0;
    const char* ldsB1 = (const char*)&Bs[0][0] + wni * 8192  + r16 * 128 + (s0 ^ 64);

    floatx4 acc[8][4];
    #pragma unroll
    for (int mi = 0; mi < 8; ++mi)
        #pragma unroll
        for (int ni = 0; ni < 4; ++ni)
            acc[mi][ni] = (floatx4)(0.f);

    // ---- prologue: A(0), B(0), B(1); leave B(1) in flight
    load_lds16(aG00, DSTA(0, 0, 0));
    load_lds16(aG01, DSTA(0, 0, 1));
    load_lds16(aG10, DSTA(0, 1, 0));
    load_lds16(aG11, DSTA(0, 1, 1));
    load_lds16(bG00, DSTB(0, 0, 0));          // bd(0) = 0 (tap0, ic0)
    load_lds16(bG01, DSTB(0, 0, 1));
    load_lds16(bG10, DSTB(0, 1, 0));
    load_lds16(bG11, DSTB(0, 1, 1));
    load_lds16(bG00 + 64, DSTB(1, 0, 0));     // bd(1) = 64 (tap0, ic1)
    load_lds16(bG01 + 64, DSTB(1, 0, 1));
    load_lds16(bG10 + 64, DSTB(1, 1, 0));
    load_lds16(bG11 + 64, DSTB(1, 1, 1));
    asm volatile("s_waitcnt vmcnt(4)" ::: "memory");
    __builtin_amdgcn_sched_barrier(0);
    BAR();

    bf16x8 af[2][2];
    bf16x8 bf[4][2];

    #pragma unroll 1
    for (int it = 0; it < 35; ++it) {
        int t0 = it * 2;
        TILE(0, t0,     true, true, 4)
        TILE(1, t0 + 1, true, true, 4)
    }
    // tiles 70, 71: no B prefetch left; tile 70 stages A(71) then drains fully
    TILE(0, 70, true,  false, 0)
    TILE(1, 71, false, false, 0)

    // ---- epilogue: * invn[b,o] + conv_b + noise*nw, LeakyReLU(0.2)
    float nwv = nw_p[0];
    #pragma unroll
    for (int ni = 0; ni < 4; ++ni) {
        int col = n0 + wni * 64 + ni * 16 + r16;         // pixel
        float nz = noise[b * NPIX + col] * nwv;
        #pragma unroll
        for (int mi = 0; mi < 8; ++mi) {
            int rowo = m0 + wmi * 128 + mi * 16 + q4 * 4; // output channel base
            #pragma unroll
            for (int rr = 0; rr < 4; ++rr) {
                float sc = invn[b * 512 + rowo + rr];
                float vv = acc[mi][ni][rr] * sc + conv_b[rowo + rr] + nz;
                out[(((size_t)b * CO + rowo + rr) << 12) + col] = vv >= 0.f ? vv : LEAK * vv;
            }
        }
    }
}

// ---------------------------------------------------------------- launch

extern "C" void kernel_launch(void* const* d_in, const int* in_sizes, int n_in,
                              void* d_out, int out_size, void* d_ws, size_t ws_size,
                              hipStream_t stream) {
    const float* imgs    = (const float*)d_in[0];
    const float* w_embs  = (const float*)d_in[1];
    const float* noise   = (const float*)d_in[2];
    const float* conv_w  = (const float*)d_in[3];
    const float* conv_b  = (const float*)d_in[4];
    const float* style_w = (const float*)d_in[5];
    const float* style_b = (const float*)d_in[6];
    const float* nw      = (const float*)d_in[7];
    float* out = (float*)d_out;

    char* ws = (char*)d_ws;
    size_t off = 0;
    __bf16* wsh = (__bf16*)(ws + off);       off += (size_t)CO * KTOT * 2;           // 4.7 MB
    __bf16* imgpad = (__bf16*)(ws + off);    off += IMGPAD_ELEMS * 2;                // 71.4 MB
    float* style = (float*)(ws + off);       off += (size_t)B_ * CI * 4;
    float* invn  = (float*)(ws + off);       off += (size_t)B_ * CO * 4;
    float* w2    = (float*)(ws + off);       off += (size_t)CO * CI * 4;

    style_kernel<<<dim3(2, B_), 256, 0, stream>>>(w_embs, style_w, style_b, style);
    w2_kernel<<<dim3(1024), 256, 0, stream>>>(conv_w, w2);
    invn_kernel<<<dim3(2, B_), 256, 0, stream>>>(w2, style, invn);
    wsh_kernel<<<dim3(CO / 4), 256, 0, stream>>>(conv_w, wsh);
    halo_kernel<<<dim3((B_ * 260 * 64 + 255) / 256), 256, 0, stream>>>(imgpad);
    imgpad_kernel<<<dim3(8, HH, B_), 256, 0, stream>>>(imgs, style, imgpad);
    conv_kernel<<<dim3(NPIX / BN, CO / BM, B_), 512, 0, stream>>>(
        wsh, imgpad, invn, conv_b, noise, nw, out);
}